// Round 5
// baseline (409.087 us; speedup 1.0000x reference)
//
#include <hip/hip_runtime.h>
#include <hip/hip_bf16.h>

// Problem constants
constexpr int       DIM        = 128;
constexpr long long CN         = 131073;               // 1 + QUEUE_K
constexpr long long OUT_ELEMS  = 256LL * 131073LL;     // 33554688
constexpr long long PROBS_OFF  = OUT_ELEMS;
constexpr long long MEMOUT_OFF = OUT_ELEMS + 1;
constexpr long long MEM_ELEMS  = 131072LL * 128LL;     // 16777216

constexpr float SCL = 20.60992915555662f;              // log2(e)/0.07

// ws layout (float indices)
constexpr int WS_INVZ  = 0;
constexpr int WS_ELPOS = 16;      // 256 floats
constexpr int WS_KMEAN = 272;     // 64*128 floats
constexpr int WS_ROWP  = 8464;    // 32 slices x 256 floats
constexpr int WS_MEMBF = 16656;   // memory as bf16: ushort[16777216] (32MB), 16B aligned

typedef __attribute__((ext_vector_type(8))) short  short8v;
typedef __attribute__((ext_vector_type(4))) float  f32x4;
typedef __attribute__((ext_vector_type(4), aligned(4))) float f32x4u;  // 4B-aligned vec4

__device__ __forceinline__ unsigned short f2bf(float x) {
  unsigned u = __float_as_uint(x);
  u += 0x7fffu + ((u >> 16) & 1u);   // RNE
  return (unsigned short)(u >> 16);
}

__device__ __forceinline__ short8v pack8(float4 a, float4 b) {
  short8v h;
  h[0] = (short)f2bf(a.x); h[1] = (short)f2bf(a.y);
  h[2] = (short)f2bf(a.z); h[3] = (short)f2bf(a.w);
  h[4] = (short)f2bf(b.x); h[5] = (short)f2bf(b.y);
  h[6] = (short)f2bf(b.z); h[7] = (short)f2bf(b.w);
  return h;
}

// Small prep: k_mean (32 blocks), l_pos (64 blocks), zero rowp (4 blocks)
__global__ __launch_bounds__(256) void k_prep(const float* __restrict__ q,
                                              const float* __restrict__ k,
                                              float* __restrict__ ws) {
  const int b = blockIdx.x, t = threadIdx.x;
  if (b < 32) {                        // k_mean per video
    int j = b * 256 + t;
    int v = j >> 7, d = j & 127;
    ws[WS_KMEAN + j] = 0.25f * (k[v*128+d] + k[(v+64)*128+d] +
                                k[(v+128)*128+d] + k[(v+192)*128+d]);
  } else if (b < 96) {                 // exp(l_pos/T): one wave per row
    int row = (b - 32) * 4 + (t >> 6);
    int lane = t & 63;
    int vid = row & 63;
    float2 qv = ((const float2*)(q + row * DIM))[lane];
    float2 kr = ((const float2*)(k + row * DIM))[lane];
    float s0 = -kr.x, s1 = -kr.y;
    #pragma unroll
    for (int c = 0; c < 4; ++c) {
      float2 kc = ((const float2*)(k + (vid + c * 64) * DIM))[lane];
      s0 += kc.x; s1 += kc.y;
    }
    float acc = qv.x * s0 + qv.y * s1;
    #pragma unroll
    for (int off = 1; off < 64; off <<= 1) acc += __shfl_xor(acc, off, 64);
    if (lane == 0) ws[WS_ELPOS + row] = exp2f(acc * (1.f / 3.f) * SCL);
  } else {                             // zero rowp (32*256 floats)
    int i = (b - 96) * 2048 + t * 8;
    float4 z = {0.f, 0.f, 0.f, 0.f};
    *(float4*)(ws + WS_ROWP + i)     = z;
    *(float4*)(ws + WS_ROWP + i + 4) = z;
  }
}

// Pass 0: read memv f32, convert in-reg, MFMA row-sums of exp; wave ks stores bf16 tile slice.
template<int NT>
__global__ __launch_bounds__(256) void k_gemm0(const float* __restrict__ memv,
                                               const float* __restrict__ q,
                                               unsigned short* __restrict__ membf,
                                               float* __restrict__ ws) {
  const int t = threadIdx.x, lane = t & 63, wave = t >> 6;
  const int g = lane >> 4, nlo = lane & 15;

  // q fragments: f32 -> bf16 in-reg (q is 128KB, L2-resident; every block reads all rows)
  short8v af[4][4];                            // [ks][mf]
  #pragma unroll
  for (int ks = 0; ks < 4; ++ks)
    #pragma unroll
    for (int mf = 0; mf < 4; ++mf) {
      const float4* src = (const float4*)(q + (wave*64 + mf*16 + nlo)*DIM + ks*32 + g*8);
      af[ks][mf] = pack8(src[0], src[1]);
    }

  float sums[4][4];
  #pragma unroll
  for (int mf = 0; mf < 4; ++mf)
    #pragma unroll
    for (int r = 0; r < 4; ++r) sums[mf][r] = 0.f;

  for (int it = 0; it < NT; ++it) {
    const long long n0 = ((long long)blockIdx.x * NT + it) * 32;
    f32x4 acc[4][2];
    f32x4 zero = {0.f, 0.f, 0.f, 0.f};
    #pragma unroll
    for (int mf = 0; mf < 4; ++mf) { acc[mf][0] = zero; acc[mf][1] = zero; }

    #pragma unroll
    for (int ks = 0; ks < 4; ++ks) {
      #pragma unroll
      for (int nf = 0; nf < 2; ++nf) {
        const long long off = (n0 + nf*16 + nlo) * DIM + ks*32 + g*8;
        const float4* src = (const float4*)(memv + off);
        short8v bfr = pack8(src[0], src[1]);
        if (wave == ks)                          // each wave persists one ks-slice
          *(short8v*)(membf + off) = bfr;
        #pragma unroll
        for (int mf = 0; mf < 4; ++mf)
          acc[mf][nf] = __builtin_amdgcn_mfma_f32_16x16x32_bf16(af[ks][mf], bfr, acc[mf][nf], 0, 0, 0);
      }
    }

    #pragma unroll
    for (int mf = 0; mf < 4; ++mf)
      #pragma unroll
      for (int r = 0; r < 4; ++r)
        sums[mf][r] += exp2f(acc[mf][0][r] * SCL) + exp2f(acc[mf][1][r] * SCL);
  }

  float* rowp = ws + WS_ROWP + (blockIdx.x & 31) * 256;
  #pragma unroll
  for (int mf = 0; mf < 4; ++mf) {
    #pragma unroll
    for (int r = 0; r < 4; ++r) {
      float s = sums[mf][r];
      s += __shfl_xor(s, 1, 16);
      s += __shfl_xor(s, 2, 16);
      s += __shfl_xor(s, 4, 16);
      s += __shfl_xor(s, 8, 16);
      if (nlo == 0) atomicAdd(&rowp[wave*64 + mf*16 + g*4 + r], s);   // D: row=4g+r
    }
  }
}

__global__ void k_fin(float* __restrict__ ws, float* __restrict__ out) {
  __shared__ float s_tot[256];
  __shared__ float s_pr[256];
  __shared__ float sh_invZ;
  int t = threadIdx.x;
  float s = ws[WS_ELPOS + t];
  float rs = s;
  for (int sl = 0; sl < 32; ++sl) rs += ws[WS_ROWP + sl * 256 + t];
  s_tot[t] = rs;
  s_pr[t] = s / rs;                     // scale-invariant
  __syncthreads();
  for (int off = 128; off > 0; off >>= 1) {
    if (t < off) { s_tot[t] += s_tot[t + off]; s_pr[t] += s_pr[t + off]; }
    __syncthreads();
  }
  if (t == 0) {
    double Z = (double)s_tot[0] * (1000000.0 / (256.0 * 131073.0));
    float invZ = (float)(1.0 / Z);
    ws[WS_INVZ] = invZ;
    sh_invZ = invZ;
    out[PROBS_OFF] = s_pr[0] * (1.f / 256.f);
  }
  __syncthreads();
  out[(long long)t * CN] = s * sh_invZ;
}

// Pass 1: bf16 tile from membf, q f32 -> af in-reg, write out[:,1:].
// Consecutive tiles per block + XCD-chunked swizzle => adjacent column spans share an XCD L2
// so the 4B-offset (odd CN) partial lines merge to full lines before HBM writeback.
template<int NT>
__global__ __launch_bounds__(256) void k_gemm1(const unsigned short* __restrict__ membf,
                                               const float* __restrict__ q,
                                               const float* __restrict__ ws,
                                               float* __restrict__ out) {
  const int t = threadIdx.x, lane = t & 63, wave = t >> 6;
  const int g = lane >> 4, nlo = lane & 15;
  const float invZ = ws[WS_INVZ];

  short8v af[4][4];
  #pragma unroll
  for (int ks = 0; ks < 4; ++ks)
    #pragma unroll
    for (int mf = 0; mf < 4; ++mf) {
      const float4* src = (const float4*)(q + (wave*64 + mf*16 + nlo)*DIM + ks*32 + g*8);
      af[ks][mf] = pack8(src[0], src[1]);
    }

  long long rowoff[4][4];                       // hoisted out-row bases
  #pragma unroll
  for (int mf = 0; mf < 4; ++mf)
    #pragma unroll
    for (int r = 0; r < 4; ++r)
      rowoff[mf][r] = (long long)(wave*64 + mf*16 + g*4 + r) * CN + 1 + nlo;

  // XCD swizzle: hw bid%8 = XCD; logical consecutive blocks share an XCD chunk.
  const int logical = (blockIdx.x & 7) * 64 + (blockIdx.x >> 3);   // grid must be 512
  const long long t0 = (long long)logical * NT;

  for (int it = 0; it < NT; ++it) {
    const long long n0 = (t0 + it) * 32;
    f32x4 acc[4][2];
    f32x4 zero = {0.f, 0.f, 0.f, 0.f};
    #pragma unroll
    for (int mf = 0; mf < 4; ++mf) { acc[mf][0] = zero; acc[mf][1] = zero; }

    #pragma unroll
    for (int ks = 0; ks < 4; ++ks) {
      short8v b0 = *(const short8v*)(membf + (n0 + nlo)      * DIM + ks*32 + g*8);
      short8v b1 = *(const short8v*)(membf + (n0 + 16 + nlo) * DIM + ks*32 + g*8);
      #pragma unroll
      for (int mf = 0; mf < 4; ++mf) {
        acc[mf][0] = __builtin_amdgcn_mfma_f32_16x16x32_bf16(af[ks][mf], b0, acc[mf][0], 0, 0, 0);
        acc[mf][1] = __builtin_amdgcn_mfma_f32_16x16x32_bf16(af[ks][mf], b1, acc[mf][1], 0, 0, 0);
      }
    }

    #pragma unroll
    for (int mf = 0; mf < 4; ++mf) {
      #pragma unroll
      for (int r = 0; r < 4; ++r) {
        out[rowoff[mf][r] + n0]      = exp2f(acc[mf][0][r] * SCL) * invZ;
        out[rowoff[mf][r] + n0 + 16] = exp2f(acc[mf][1][r] * SCL) * invZ;
      }
    }
  }
}

__global__ void k_copy(const float* __restrict__ memv, const float* __restrict__ ws,
                       float* __restrict__ out) {
  float* dst = out + MEMOUT_OFF;        // element 0 at 4B-odd float offset
  const float* km = ws + WS_KMEAN;
  long long gid = blockIdx.x * 256LL + threadIdx.x;
  if (gid == 0) {                       // scalar edges
    dst[0] = km[0]; dst[1] = km[1]; dst[2] = km[2];
    dst[8191] = km[8191];
    dst[8192] = memv[8192]; dst[8193] = memv[8193]; dst[8194] = memv[8194];
    dst[MEM_ELEMS - 1] = memv[MEM_ELEMS - 1];
  }
  if (gid < 2047) {                     // km region [3, 8191), dst 16B-aligned
    long long base = 3 + gid * 4;
    f32x4u v = *(const f32x4u*)(km + base);
    *(f32x4u*)(dst + base) = v;
  }
  // bulk [8195, MEM_ELEMS-1): dst 16B-aligned, src 4B-misaligned
  const long long NGB = (MEM_ELEMS - 1 - 8195) / 4;   // 4192255
  const long long stride = (long long)gridDim.x * 256LL;
  for (long long j = gid; j < NGB; j += stride) {
    long long base = 8195 + j * 4;
    f32x4u v = *(const f32x4u*)(memv + base);
    *(f32x4u*)(dst + base) = v;
  }
}

extern "C" void kernel_launch(void* const* d_in, const int* in_sizes, int n_in,
                              void* d_out, int out_size, void* d_ws, size_t ws_size,
                              hipStream_t stream) {
  (void)in_sizes; (void)n_in; (void)out_size; (void)ws_size;
  const float* q    = (const float*)d_in[0];
  const float* k    = (const float*)d_in[1];
  const float* memv = (const float*)d_in[2];
  float* out = (float*)d_out;
  float* ws  = (float*)d_ws;
  unsigned short* membf = (unsigned short*)(ws + WS_MEMBF);

  hipLaunchKernelGGL(k_prep, dim3(100), dim3(256), 0, stream, q, k, ws);
  hipLaunchKernelGGL((k_gemm0<8>), dim3(512), dim3(256), 0, stream, memv, q, membf, ws);
  hipLaunchKernelGGL(k_fin,  dim3(1),   dim3(256), 0, stream, ws, out);
  hipLaunchKernelGGL((k_gemm1<8>), dim3(512), dim3(256), 0, stream, membf, q, ws, out);
  hipLaunchKernelGGL(k_copy, dim3(2048), dim3(256), 0, stream, memv, ws, out);
}